// Round 1
// baseline (134.788 us; speedup 1.0000x reference)
//
#include <hip/hip_runtime.h>

// BiLingual embedding-bag-sum:
//   out_pri[b,d] = sum_s emb_pri[idx_pri[b,s], d]   (B=4096, S=200, D=64)
//   out_sec[b,d] = sum_s emb_sec[idx_sec[b,s], d]
// d_out = [out_pri (4096*64) | out_sec (4096*64)] fp32.
//
// One wave per (table,row). Wave split into 4 quarter-waves of 16 lanes;
// each quarter handles a different token s, each lane loads float4 of the
// 64-float embedding row (16 lanes x 16B = 256B coalesced). 4 independent
// gather chains/wave/iter hide L2/L3 gather latency. Cross-quarter shuffle
// reduction at the end; lanes 0..15 store one float4 each (coalesced).

#define BB 4096
#define SS 200
#define DD 64

__global__ __launch_bounds__(256) void bilingual_embed_sum(
    const int* __restrict__ idx_pri,
    const int* __restrict__ idx_sec,
    const float* __restrict__ emb_pri,
    const float* __restrict__ emb_sec,
    float* __restrict__ out)
{
    const int wave = (int)((blockIdx.x * blockDim.x + threadIdx.x) >> 6);
    const int lane = (int)(threadIdx.x & 63);
    const int table = wave >> 12;      // 0 = pri, 1 = sec
    const int b     = wave & (BB - 1);

    const int*   idx = table ? idx_sec : idx_pri;
    const float* emb = table ? emb_sec : emb_pri;
    float* outp = out + (size_t)table * BB * DD + (size_t)b * DD;

    const int q   = lane >> 4;   // quarter-wave id: which token offset
    const int l16 = lane & 15;   // float4 slot within the 64-float row

    const int* row_idx = idx + b * SS;

    float4 acc = make_float4(0.f, 0.f, 0.f, 0.f);

    #pragma unroll 5
    for (int s0 = 0; s0 < SS; s0 += 4) {
        const int i = row_idx[s0 + q];                       // broadcast within quarter
        const float4* rp = (const float4*)(emb + (size_t)i * DD);
        const float4 v = rp[l16];
        acc.x += v.x; acc.y += v.y; acc.z += v.z; acc.w += v.w;
    }

    // Reduce the 4 quarter-wave partial sums (same l16, different q).
    acc.x += __shfl_down(acc.x, 32);
    acc.y += __shfl_down(acc.y, 32);
    acc.z += __shfl_down(acc.z, 32);
    acc.w += __shfl_down(acc.w, 32);
    acc.x += __shfl_down(acc.x, 16);
    acc.y += __shfl_down(acc.y, 16);
    acc.z += __shfl_down(acc.z, 16);
    acc.w += __shfl_down(acc.w, 16);

    if (lane < 16) {
        ((float4*)outp)[l16] = acc;
    }
}

extern "C" void kernel_launch(void* const* d_in, const int* in_sizes, int n_in,
                              void* d_out, int out_size, void* d_ws, size_t ws_size,
                              hipStream_t stream) {
    const int*   idx_pri = (const int*)d_in[0];
    const int*   idx_sec = (const int*)d_in[1];
    const float* emb_pri = (const float*)d_in[2];
    const float* emb_sec = (const float*)d_in[3];
    float* out = (float*)d_out;

    // 2 tables * 4096 rows = 8192 waves; 4 waves per 256-thread block.
    const int n_waves = 2 * BB;
    const int block = 256;
    const int grid = n_waves / (block / 64);   // 2048

    bilingual_embed_sum<<<grid, block, 0, stream>>>(idx_pri, idx_sec, emb_pri, emb_sec, out);
}

// Round 2
// 131.405 us; speedup vs baseline: 1.0257x; 1.0257x over previous
//
#include <hip/hip_runtime.h>

// BiLingual embedding-bag-sum:
//   out_pri[b,d] = sum_s emb_pri[idx_pri[b,s], d]   (B=4096, S=200, D=64)
//   out_sec[b,d] = sum_s emb_sec[idx_sec[b,s], d]
// d_out = [out_pri (4096*64) | out_sec (4096*64)] fp32.
//
// R2: one wave per (table,row); all 200 indices staged into LDS up front
// (coalesced int4), so the main loop's gathers depend only on a cheap
// ds_read, not a global index load. Unroll 10 -> ~10 gathers in flight per
// wave (vs ~5 before, and no idx/gather latency serialization).
// Wave split into 4 quarter-waves of 16 lanes; quarter q handles token
// s0+q, each lane loads float4 of the 256B row (fully coalesced).
// Cross-quarter shuffle reduction; lanes 0..15 store one float4 (coalesced).

#define BB 4096
#define SS 200
#define DD 64

__global__ __launch_bounds__(256) void bilingual_embed_sum(
    const int* __restrict__ idx_pri,
    const int* __restrict__ idx_sec,
    const float* __restrict__ emb_pri,
    const float* __restrict__ emb_sec,
    float* __restrict__ out)
{
    __shared__ int sidx[4][SS];   // 4 waves/block x 200 idx = 3.2 KB

    const int w    = (int)(threadIdx.x >> 6);      // wave within block
    const int lane = (int)(threadIdx.x & 63);
    const int wave = (int)(blockIdx.x * 4 + w);    // global wave id
    const int table = wave >> 12;                  // 0 = pri, 1 = sec
    const int b     = wave & (BB - 1);

    const int*   idx = table ? idx_sec : idx_pri;
    const float* emb = table ? emb_sec : emb_pri;
    float* outp = out + (size_t)table * BB * DD + (size_t)b * DD;

    // Stage this wave's 200 indices: 50 int4 loads, lanes 0..49.
    const int* row_idx = idx + b * SS;             // 800B-aligned
    if (lane < SS / 4) {
        const int4 v = ((const int4*)row_idx)[lane];
        sidx[w][lane * 4 + 0] = v.x;
        sidx[w][lane * 4 + 1] = v.y;
        sidx[w][lane * 4 + 2] = v.z;
        sidx[w][lane * 4 + 3] = v.w;
    }
    __syncthreads();

    const int q   = lane >> 4;   // quarter-wave id: token offset within group of 4
    const int l16 = lane & 15;   // float4 slot within the 64-float row

    float4 acc = make_float4(0.f, 0.f, 0.f, 0.f);

    #pragma unroll 10
    for (int s0 = 0; s0 < SS; s0 += 4) {
        const int i = sidx[w][s0 + q];             // LDS broadcast within quarter
        const float4* rp = (const float4*)(emb + (size_t)i * DD);
        const float4 v = rp[l16];
        acc.x += v.x; acc.y += v.y; acc.z += v.z; acc.w += v.w;
    }

    // Reduce the 4 quarter-wave partial sums (same l16, different q).
    acc.x += __shfl_down(acc.x, 32);
    acc.y += __shfl_down(acc.y, 32);
    acc.z += __shfl_down(acc.z, 32);
    acc.w += __shfl_down(acc.w, 32);
    acc.x += __shfl_down(acc.x, 16);
    acc.y += __shfl_down(acc.y, 16);
    acc.z += __shfl_down(acc.z, 16);
    acc.w += __shfl_down(acc.w, 16);

    if (lane < 16) {
        ((float4*)outp)[l16] = acc;
    }
}

extern "C" void kernel_launch(void* const* d_in, const int* in_sizes, int n_in,
                              void* d_out, int out_size, void* d_ws, size_t ws_size,
                              hipStream_t stream) {
    const int*   idx_pri = (const int*)d_in[0];
    const int*   idx_sec = (const int*)d_in[1];
    const float* emb_pri = (const float*)d_in[2];
    const float* emb_sec = (const float*)d_in[3];
    float* out = (float*)d_out;

    // 2 tables * 4096 rows = 8192 waves; 4 waves per 256-thread block.
    const int n_waves = 2 * BB;
    const int block = 256;
    const int grid = n_waves / (block / 64);   // 2048

    bilingual_embed_sum<<<grid, block, 0, stream>>>(idx_pri, idx_sec, emb_pri, emb_sec, out);
}